// Round 1
// baseline (48321.625 us; speedup 1.0000x reference)
//
#include <hip/hip_runtime.h>

#define D_MODEL 512
#define T_ENC 512
#define BATCH 64
#define SEQ_LEN 128
#define TB (T_ENC * BATCH)  // 32768

// ---------------------------------------------------------------------------
// Generic 64x64-tile fp32 GEMM: C = act(A @ B(^T) + bias)
// A: [M,K] row-major. B: [K,N] row-major if !BT, else [N,K] row-major.
// M,N multiples of 64; K multiple of 16.
// ---------------------------------------------------------------------------
template <bool BT, bool RELU>
__global__ __launch_bounds__(256) void gemm64(
    const float* __restrict__ A, const float* __restrict__ B,
    const float* __restrict__ bias, float* __restrict__ C,
    int M, int N, int K) {
  __shared__ float As[16][64];
  __shared__ float Bs[16][64];
  const int m0 = blockIdx.x * 64, n0 = blockIdx.y * 64;
  const int tid = threadIdx.x;
  const int r0 = (tid >> 4) << 2;  // 0..60 step 4
  const int c0 = (tid & 15) << 2;  // 0..60 step 4
  const int arow = tid >> 2, aks = (tid & 3) << 2;

  float acc[4][4] = {};

  for (int k0 = 0; k0 < K; k0 += 16) {
    // A tile: 64 rows x 16 k
    {
      const float4 av =
          *reinterpret_cast<const float4*>(&A[(m0 + arow) * K + k0 + aks]);
      As[aks + 0][arow] = av.x;
      As[aks + 1][arow] = av.y;
      As[aks + 2][arow] = av.z;
      As[aks + 3][arow] = av.w;
    }
    if (!BT) {
      const int bk = tid >> 4, bns = (tid & 15) << 2;
      const float4 bv =
          *reinterpret_cast<const float4*>(&B[(k0 + bk) * N + n0 + bns]);
      Bs[bk][bns + 0] = bv.x;
      Bs[bk][bns + 1] = bv.y;
      Bs[bk][bns + 2] = bv.z;
      Bs[bk][bns + 3] = bv.w;
    } else {
      const int bn = tid >> 2, bks = (tid & 3) << 2;
      const float4 bv =
          *reinterpret_cast<const float4*>(&B[(n0 + bn) * K + k0 + bks]);
      Bs[bks + 0][bn] = bv.x;
      Bs[bks + 1][bn] = bv.y;
      Bs[bks + 2][bn] = bv.z;
      Bs[bks + 3][bn] = bv.w;
    }
    __syncthreads();
#pragma unroll
    for (int k = 0; k < 16; ++k) {
      float a[4], b[4];
#pragma unroll
      for (int i = 0; i < 4; ++i) a[i] = As[k][r0 + i];
#pragma unroll
      for (int j = 0; j < 4; ++j) b[j] = Bs[k][c0 + j];
#pragma unroll
      for (int i = 0; i < 4; ++i)
#pragma unroll
        for (int j = 0; j < 4; ++j) acc[i][j] = fmaf(a[i], b[j], acc[i][j]);
    }
    __syncthreads();
  }

#pragma unroll
  for (int i = 0; i < 4; ++i) {
#pragma unroll
    for (int j = 0; j < 4; ++j) {
      float v = acc[i][j];
      if (bias) v += bias[n0 + c0 + j];
      if (RELU) v = fmaxf(v, 0.f);
      C[(m0 + r0 + i) * N + n0 + c0 + j] = v;
    }
  }
}

// ---------------------------------------------------------------------------
// Fused attention-score kernel. For each row r = t*64+b (M = 32768):
//   s1 = relu(yproj[b] + encproj[r])           [512]
//   s2 = relu(s1 @ a2_w + a2_b)                [128]
//   scores[r] = s2 @ a3_w + a3_b
// Tile: 128 rows x 128 cols per block, K = 512 in chunks of 16.
// ---------------------------------------------------------------------------
__global__ __launch_bounds__(256) void scores_kernel(
    const float* __restrict__ encproj, const float* __restrict__ yproj,
    const float* __restrict__ a2w, const float* __restrict__ a2b,
    const float* __restrict__ a3w, const float* __restrict__ a3bp,
    float* __restrict__ scores) {
  __shared__ float As[16][128];
  __shared__ float Bs[16][128];
  const int row0 = blockIdx.x * 128;
  const int tid = threadIdx.x;
  const int r0 = (tid >> 4) << 3;  // 0..120 step 8
  const int cB = tid & 15;

  float acc[8][8] = {};

  for (int k0 = 0; k0 < 512; k0 += 16) {
    // A tile: 128 rows x 16 k, with fused relu(encproj + yproj)
#pragma unroll
    for (int rep = 0; rep < 2; ++rep) {
      const int idx = rep * 1024 + tid * 4;
      const int row = idx >> 4;       // 0..127
      const int ks = idx & 15;        // 0,4,8,12
      const float4 ep = *reinterpret_cast<const float4*>(
          &encproj[(row0 + row) * 512 + k0 + ks]);
      const float4 yp = *reinterpret_cast<const float4*>(
          &yproj[(row & 63) * 512 + k0 + ks]);
      As[ks + 0][row] = fmaxf(ep.x + yp.x, 0.f);
      As[ks + 1][row] = fmaxf(ep.y + yp.y, 0.f);
      As[ks + 2][row] = fmaxf(ep.z + yp.z, 0.f);
      As[ks + 3][row] = fmaxf(ep.w + yp.w, 0.f);
    }
    // B tile: 16 k x 128 n
    {
      const int bk = tid >> 4;
      const int bns = (tid & 15) << 3;
      const float4 b0 =
          *reinterpret_cast<const float4*>(&a2w[(k0 + bk) * 128 + bns]);
      const float4 b1 =
          *reinterpret_cast<const float4*>(&a2w[(k0 + bk) * 128 + bns + 4]);
      Bs[bk][bns + 0] = b0.x;
      Bs[bk][bns + 1] = b0.y;
      Bs[bk][bns + 2] = b0.z;
      Bs[bk][bns + 3] = b0.w;
      Bs[bk][bns + 4] = b1.x;
      Bs[bk][bns + 5] = b1.y;
      Bs[bk][bns + 6] = b1.z;
      Bs[bk][bns + 7] = b1.w;
    }
    __syncthreads();
#pragma unroll
    for (int k = 0; k < 16; ++k) {
      float a[8], b[8];
      const float4 a0 = *reinterpret_cast<const float4*>(&As[k][r0]);
      const float4 a1 = *reinterpret_cast<const float4*>(&As[k][r0 + 4]);
      a[0] = a0.x; a[1] = a0.y; a[2] = a0.z; a[3] = a0.w;
      a[4] = a1.x; a[5] = a1.y; a[6] = a1.z; a[7] = a1.w;
#pragma unroll
      for (int j = 0; j < 8; ++j) b[j] = Bs[k][cB + (j << 4)];
#pragma unroll
      for (int i = 0; i < 8; ++i)
#pragma unroll
        for (int j = 0; j < 8; ++j) acc[i][j] = fmaf(a[i], b[j], acc[i][j]);
    }
    __syncthreads();
  }

  // Epilogue: relu + a2 bias, dot with a3_w, reduce across the 16 col-lanes.
  float a3[8], a2bv[8];
#pragma unroll
  for (int j = 0; j < 8; ++j) {
    a3[j] = a3w[cB + (j << 4)];
    a2bv[j] = a2b[cB + (j << 4)];
  }
  const float a3b = *a3bp;
#pragma unroll
  for (int i = 0; i < 8; ++i) {
    float p = 0.f;
#pragma unroll
    for (int j = 0; j < 8; ++j)
      p = fmaf(fmaxf(acc[i][j] + a2bv[j], 0.f), a3[j], p);
    p += __shfl_xor(p, 1);
    p += __shfl_xor(p, 2);
    p += __shfl_xor(p, 4);
    p += __shfl_xor(p, 8);
    if (cB == 0) scores[row0 + r0 + i] = p + a3b;
  }
}

// ---------------------------------------------------------------------------
// Softmax over T (=512) for each batch column b. scores layout [T,B] (=t*64+b).
// ---------------------------------------------------------------------------
__global__ __launch_bounds__(256) void softmax_kernel(
    const float* __restrict__ scores, float* __restrict__ att) {
  const int b = blockIdx.x;
  const int tid = threadIdx.x;
  __shared__ float red[256];
  const float v0 = scores[tid * 64 + b];
  const float v1 = scores[(tid + 256) * 64 + b];
  red[tid] = fmaxf(v0, v1);
  __syncthreads();
  for (int s = 128; s > 0; s >>= 1) {
    if (tid < s) red[tid] = fmaxf(red[tid], red[tid + s]);
    __syncthreads();
  }
  const float m = red[0];
  __syncthreads();
  const float e0 = __expf(v0 - m) , e1 = __expf(v1 - m);
  red[tid] = e0 + e1;
  __syncthreads();
  for (int s = 128; s > 0; s >>= 1) {
    if (tid < s) red[tid] += red[tid + s];
    __syncthreads();
  }
  const float inv = 1.f / red[0];
  att[tid * 64 + b] = e0 * inv;
  att[(tid + 256) * 64 + b] = e1 * inv;
}

// ---------------------------------------------------------------------------
// ctx[b] = sum_t att[t,b] * enc_x[t,b,:]; writes comb = [y, ctx] ([64,1024]).
// Grid: 128 blocks = (b, half); 256 threads cover 256 d's.
// ---------------------------------------------------------------------------
__global__ __launch_bounds__(256) void ctx_concat_kernel(
    const float* __restrict__ att, const float* __restrict__ enc_x,
    const float* __restrict__ y, float* __restrict__ comb) {
  const int b = blockIdx.x >> 1;
  const int half = blockIdx.x & 1;
  const int d = half * 256 + threadIdx.x;
  float acc0 = 0.f, acc1 = 0.f, acc2 = 0.f, acc3 = 0.f;
  for (int t = 0; t < 512; t += 4) {
    acc0 = fmaf(att[(t + 0) * 64 + b], enc_x[((t + 0) * 64 + b) * 512 + d], acc0);
    acc1 = fmaf(att[(t + 1) * 64 + b], enc_x[((t + 1) * 64 + b) * 512 + d], acc1);
    acc2 = fmaf(att[(t + 2) * 64 + b], enc_x[((t + 2) * 64 + b) * 512 + d], acc2);
    acc3 = fmaf(att[(t + 3) * 64 + b], enc_x[((t + 3) * 64 + b) * 512 + d], acc3);
  }
  comb[b * 1024 + 512 + d] = (acc0 + acc1) + (acc2 + acc3);
  comb[b * 1024 + d] = y[b * 512 + d];
}

// ---------------------------------------------------------------------------
// GRU gate fusion: h = (1-z)*n + z*h, optional output write.
// ---------------------------------------------------------------------------
__global__ __launch_bounds__(256) void gate_kernel(
    const float* __restrict__ gi, const float* __restrict__ gh,
    float* __restrict__ h, float* __restrict__ out) {
  const int idx = blockIdx.x * 256 + threadIdx.x;  // 0..32767
  const int b = idx >> 9, j = idx & 511;
  const int base = b * 1536;
  const float ir = gi[base + j], iz = gi[base + 512 + j], in_ = gi[base + 1024 + j];
  const float hr = gh[base + j], hz = gh[base + 512 + j], hn = gh[base + 1024 + j];
  const float r = 1.f / (1.f + expf(-(ir + hr)));
  const float z = 1.f / (1.f + expf(-(iz + hz)));
  const float n = tanhf(in_ + r * hn);
  const float hnew = (1.f - z) * n + z * h[idx];
  h[idx] = hnew;
  if (out) out[idx] = hnew;
}

__global__ __launch_bounds__(256) void init_kernel(
    const float* __restrict__ enc_x, float* __restrict__ y0,
    float* __restrict__ h0, float* __restrict__ h1) {
  const int idx = blockIdx.x * 256 + threadIdx.x;  // 0..32767
  y0[idx] = 0.f;
  const float v = enc_x[511 * 32768 + idx];
  h0[idx] = v;
  h1[idx] = v;
}

// ---------------------------------------------------------------------------
extern "C" void kernel_launch(void* const* d_in, const int* in_sizes, int n_in,
                              void* d_out, int out_size, void* d_ws,
                              size_t ws_size, hipStream_t stream) {
  const float* enc_x = (const float*)d_in[0];
  // d_in[1] = seq_len (always 128 for this problem)
  const float* a1_w = (const float*)d_in[2];
  const float* a1_b = (const float*)d_in[3];
  const float* a2_w = (const float*)d_in[4];
  const float* a2_b = (const float*)d_in[5];
  const float* a3_w = (const float*)d_in[6];
  const float* a3_b = (const float*)d_in[7];
  const float* t1_w = (const float*)d_in[8];
  const float* t1_b = (const float*)d_in[9];
  const float* t2_w = (const float*)d_in[10];
  const float* t2_b = (const float*)d_in[11];
  const float* w_ih = (const float*)d_in[12];
  const float* w_hh = (const float*)d_in[13];
  const float* b_ih = (const float*)d_in[14];
  const float* b_hh = (const float*)d_in[15];
  float* out = (float*)d_out;

  float* ws = (float*)d_ws;
  float* encproj = ws; ws += TB * 512;      // 16.7M floats
  float* yproj = ws;   ws += 64 * 512;
  float* scores = ws;  ws += TB;
  float* att = ws;     ws += TB;
  float* comb = ws;    ws += 64 * 1024;
  float* x1 = ws;      ws += 64 * 512;
  float* xv = ws;      ws += 64 * 512;
  float* gi = ws;      ws += 64 * 1536;
  float* gh = ws;      ws += 64 * 1536;
  float* h0 = ws;      ws += 64 * 512;
  float* h1 = ws;      ws += 64 * 512;
  float* y0 = ws;      ws += 64 * 512;

  init_kernel<<<128, 256, 0, stream>>>(enc_x, y0, h0, h1);
  // encproj = enc_x @ a1_w[D:, :] + a1_b   (step-invariant, done once)
  gemm64<false, false><<<dim3(512, 8), 256, 0, stream>>>(
      enc_x, a1_w + 512 * 512, a1_b, encproj, TB, 512, 512);

  for (int t = 0; t < SEQ_LEN; ++t) {
    const float* y = (t == 0) ? y0 : h1;
    // yproj = y @ a1_w[:D, :]
    gemm64<false, false><<<dim3(1, 8), 256, 0, stream>>>(
        y, a1_w, nullptr, yproj, 64, 512, 512);
    scores_kernel<<<256, 256, 0, stream>>>(encproj, yproj, a2_w, a2_b, a3_w,
                                           a3_b, scores);
    softmax_kernel<<<64, 256, 0, stream>>>(scores, att);
    ctx_concat_kernel<<<128, 256, 0, stream>>>(att, enc_x, y, comb);
    // transform MLP
    gemm64<false, true><<<dim3(1, 8), 256, 0, stream>>>(
        comb, t1_w, t1_b, x1, 64, 512, 1024);
    gemm64<false, true><<<dim3(1, 8), 256, 0, stream>>>(
        x1, t2_w, t2_b, xv, 64, 512, 512);
    // GRU layer 0
    gemm64<true, false><<<dim3(1, 24), 256, 0, stream>>>(
        xv, w_ih, b_ih, gi, 64, 1536, 512);
    gemm64<true, false><<<dim3(1, 24), 256, 0, stream>>>(
        h0, w_hh, b_hh, gh, 64, 1536, 512);
    gate_kernel<<<128, 256, 0, stream>>>(gi, gh, h0, nullptr);
    // GRU layer 1
    gemm64<true, false><<<dim3(1, 24), 256, 0, stream>>>(
        h0, w_ih + 1536 * 512, b_ih + 1536, gi, 64, 1536, 512);
    gemm64<true, false><<<dim3(1, 24), 256, 0, stream>>>(
        h1, w_hh + 1536 * 512, b_hh + 1536, gh, 64, 1536, 512);
    gate_kernel<<<128, 256, 0, stream>>>(gi, gh, h1, out + t * TB);
  }
}

// Round 2
// 30709.964 us; speedup vs baseline: 1.5735x; 1.5735x over previous
//
#include <hip/hip_runtime.h>

#define D_MODEL 512
#define T_ENC 512
#define BATCH 64
#define SEQ_LEN 128
#define TB (T_ENC * BATCH)  // 32768

typedef __attribute__((ext_vector_type(8))) short bf16x8;
typedef __attribute__((ext_vector_type(4))) float f32x4;

// round-to-nearest-even float -> bf16 (as raw short), and back
__device__ __forceinline__ short f2bf(float f) {
  unsigned u = __float_as_uint(f);
  u += 0x7fffu + ((u >> 16) & 1u);
  return (short)(u >> 16);
}
__device__ __forceinline__ float bf2f(short s) {
  return __uint_as_float(((unsigned)(unsigned short)s) << 16);
}

// ---------------------------------------------------------------------------
// Generic 64x64-tile fp32 GEMM body: C = act(A @ B(^T) + bias)
// ---------------------------------------------------------------------------
template <bool BT, bool RELU>
__device__ __forceinline__ void gemm64_body(
    const float* __restrict__ A, const float* __restrict__ B,
    const float* __restrict__ bias, float* __restrict__ C,
    int M, int N, int K) {
  __shared__ float As[16][64];
  __shared__ float Bs[16][64];
  const int m0 = blockIdx.x * 64, n0 = blockIdx.y * 64;
  const int tid = threadIdx.x;
  const int r0 = (tid >> 4) << 2;
  const int c0 = (tid & 15) << 2;
  const int arow = tid >> 2, aks = (tid & 3) << 2;

  float acc[4][4] = {};

  for (int k0 = 0; k0 < K; k0 += 16) {
    {
      const float4 av =
          *reinterpret_cast<const float4*>(&A[(m0 + arow) * K + k0 + aks]);
      As[aks + 0][arow] = av.x;
      As[aks + 1][arow] = av.y;
      As[aks + 2][arow] = av.z;
      As[aks + 3][arow] = av.w;
    }
    if (!BT) {
      const int bk = tid >> 4, bns = (tid & 15) << 2;
      const float4 bv =
          *reinterpret_cast<const float4*>(&B[(k0 + bk) * N + n0 + bns]);
      Bs[bk][bns + 0] = bv.x;
      Bs[bk][bns + 1] = bv.y;
      Bs[bk][bns + 2] = bv.z;
      Bs[bk][bns + 3] = bv.w;
    } else {
      const int bn = tid >> 2, bks = (tid & 3) << 2;
      const float4 bv =
          *reinterpret_cast<const float4*>(&B[(n0 + bn) * K + k0 + bks]);
      Bs[bks + 0][bn] = bv.x;
      Bs[bks + 1][bn] = bv.y;
      Bs[bks + 2][bn] = bv.z;
      Bs[bks + 3][bn] = bv.w;
    }
    __syncthreads();
#pragma unroll
    for (int k = 0; k < 16; ++k) {
      float a[4], b[4];
#pragma unroll
      for (int i = 0; i < 4; ++i) a[i] = As[k][r0 + i];
#pragma unroll
      for (int j = 0; j < 4; ++j) b[j] = Bs[k][c0 + j];
#pragma unroll
      for (int i = 0; i < 4; ++i)
#pragma unroll
        for (int j = 0; j < 4; ++j) acc[i][j] = fmaf(a[i], b[j], acc[i][j]);
    }
    __syncthreads();
  }

#pragma unroll
  for (int i = 0; i < 4; ++i) {
#pragma unroll
    for (int j = 0; j < 4; ++j) {
      float v = acc[i][j];
      if (bias) v += bias[n0 + c0 + j];
      if (RELU) v = fmaxf(v, 0.f);
      C[(m0 + r0 + i) * N + n0 + c0 + j] = v;
    }
  }
}

template <bool BT, bool RELU>
__global__ __launch_bounds__(256) void gemm64(
    const float* __restrict__ A, const float* __restrict__ B,
    const float* __restrict__ bias, float* __restrict__ C,
    int M, int N, int K) {
  gemm64_body<BT, RELU>(A, B, bias, C, M, N, K);
}

// Two GRU GEMMs (gi, gh) in one launch via blockIdx.z.
__global__ __launch_bounds__(256) void gru_pair(
    const float* __restrict__ A0, const float* __restrict__ B0,
    const float* __restrict__ bias0, float* __restrict__ C0,
    const float* __restrict__ A1, const float* __restrict__ B1,
    const float* __restrict__ bias1, float* __restrict__ C1) {
  if (blockIdx.z == 0)
    gemm64_body<true, false>(A0, B0, bias0, C0, 64, 1536, 512);
  else
    gemm64_body<true, false>(A1, B1, bias1, C1, 64, 1536, 512);
}

// ---------------------------------------------------------------------------
// Pre-split a2_w [512][128] fp32 -> a2wT hi/lo [128][512] bf16 (one-time).
// ---------------------------------------------------------------------------
__global__ __launch_bounds__(256) void split_a2w(
    const float* __restrict__ a2w, short* __restrict__ hi,
    short* __restrict__ lo) {
  const int idx = blockIdx.x * 256 + threadIdx.x;  // 0..65535
  const int k = idx >> 7, n = idx & 127;
  const float v = a2w[k * 128 + n];
  const short h = f2bf(v);
  hi[n * 512 + k] = h;
  lo[n * 512 + k] = f2bf(v - bf2f(h));
}

// ---------------------------------------------------------------------------
// MFMA attention-score kernel with 3-pass bf16 split precision.
// For each row r = t*64+b (M = 32768):
//   s1 = relu(yproj[b] + encproj[r])  [512]
//   s2 = relu(s1 @ a2_w + a2_b)       [128]
//   scores[r] = s2 @ a3_w + a3_b
// Block: 128 rows x 128 cols, K in chunks of 64, 4 waves.
// ---------------------------------------------------------------------------
__global__ __launch_bounds__(256) void scores_mfma(
    const float* __restrict__ encproj, const float* __restrict__ yproj,
    const short* __restrict__ bThi, const short* __restrict__ bTlo,
    const float* __restrict__ a2b, const float* __restrict__ a3w,
    const float* __restrict__ a3bp, float* __restrict__ scores) {
  __shared__ short Ah[128 * 64];
  __shared__ short Al[128 * 64];
  __shared__ short Bh[128 * 64];
  __shared__ short Bl[128 * 64];
  const int tid = threadIdx.x;
  const int row0 = blockIdx.x * 128;
  const int wave = tid >> 6, lane = tid & 63;
  const int lrow = lane & 15, kg = lane >> 4;

  f32x4 acc[2][8];
#pragma unroll
  for (int i = 0; i < 2; ++i)
#pragma unroll
    for (int j = 0; j < 8; ++j) acc[i][j] = {0.f, 0.f, 0.f, 0.f};

  for (int c = 0; c < 8; ++c) {
    const int k0 = c * 64;
    // ---- stage A: relu(encproj+yproj), split hi/lo, XOR-swizzled ----
#pragma unroll
    for (int it = 0; it < 4; ++it) {
      const int g = tid + it * 256;  // 0..1023
      const int row = g >> 3, s = g & 7;
      const int k = k0 + s * 8;
      const float4 e0 =
          *reinterpret_cast<const float4*>(&encproj[(row0 + row) * 512 + k]);
      const float4 e1 = *reinterpret_cast<const float4*>(
          &encproj[(row0 + row) * 512 + k + 4]);
      const float4 p0 =
          *reinterpret_cast<const float4*>(&yproj[(row & 63) * 512 + k]);
      const float4 p1 =
          *reinterpret_cast<const float4*>(&yproj[(row & 63) * 512 + k + 4]);
      float v[8] = {fmaxf(e0.x + p0.x, 0.f), fmaxf(e0.y + p0.y, 0.f),
                    fmaxf(e0.z + p0.z, 0.f), fmaxf(e0.w + p0.w, 0.f),
                    fmaxf(e1.x + p1.x, 0.f), fmaxf(e1.y + p1.y, 0.f),
                    fmaxf(e1.z + p1.z, 0.f), fmaxf(e1.w + p1.w, 0.f)};
      bf16x8 vh, vl;
#pragma unroll
      for (int j = 0; j < 8; ++j) {
        const short h = f2bf(v[j]);
        vh[j] = h;
        vl[j] = f2bf(v[j] - bf2f(h));
      }
      const int off = row * 64 + ((s ^ (row & 7)) << 3);
      *reinterpret_cast<bf16x8*>(&Ah[off]) = vh;
      *reinterpret_cast<bf16x8*>(&Al[off]) = vl;
    }
    // ---- stage B: pre-split a2wT chunks ----
#pragma unroll
    for (int it = 0; it < 4; ++it) {
      const int g = tid + it * 256;
      const int n = g >> 3, s = g & 7;
      const int off = n * 64 + ((s ^ (n & 7)) << 3);
      *reinterpret_cast<bf16x8*>(&Bh[off]) =
          *reinterpret_cast<const bf16x8*>(&bThi[n * 512 + k0 + s * 8]);
      *reinterpret_cast<bf16x8*>(&Bl[off]) =
          *reinterpret_cast<const bf16x8*>(&bTlo[n * 512 + k0 + s * 8]);
    }
    __syncthreads();
    // ---- compute: 2 MFMA K-steps of 32 ----
#pragma unroll
    for (int ks = 0; ks < 2; ++ks) {
      const int sIdx = ks * 4 + kg;
      bf16x8 ah[2], al[2], bh[8], bl[8];
#pragma unroll
      for (int rt = 0; rt < 2; ++rt) {
        const int row = wave * 32 + rt * 16 + lrow;
        const int off = row * 64 + ((sIdx ^ (row & 7)) << 3);
        ah[rt] = *reinterpret_cast<const bf16x8*>(&Ah[off]);
        al[rt] = *reinterpret_cast<const bf16x8*>(&Al[off]);
      }
#pragma unroll
      for (int ct = 0; ct < 8; ++ct) {
        const int n = ct * 16 + lrow;
        const int off = n * 64 + ((sIdx ^ (n & 7)) << 3);
        bh[ct] = *reinterpret_cast<const bf16x8*>(&Bh[off]);
        bl[ct] = *reinterpret_cast<const bf16x8*>(&Bl[off]);
      }
#pragma unroll
      for (int rt = 0; rt < 2; ++rt)
#pragma unroll
        for (int ct = 0; ct < 8; ++ct) {
          acc[rt][ct] = __builtin_amdgcn_mfma_f32_16x16x32_bf16(
              ah[rt], bh[ct], acc[rt][ct], 0, 0, 0);
          acc[rt][ct] = __builtin_amdgcn_mfma_f32_16x16x32_bf16(
              al[rt], bh[ct], acc[rt][ct], 0, 0, 0);
          acc[rt][ct] = __builtin_amdgcn_mfma_f32_16x16x32_bf16(
              ah[rt], bl[ct], acc[rt][ct], 0, 0, 0);
        }
    }
    __syncthreads();
  }

  // ---- epilogue: relu(+a2b), dot a3w, reduce 16 col-lanes ----
  float a3v[8], a2bv[8];
#pragma unroll
  for (int ct = 0; ct < 8; ++ct) {
    a3v[ct] = a3w[ct * 16 + lrow];
    a2bv[ct] = a2b[ct * 16 + lrow];
  }
  const float a3b = *a3bp;
#pragma unroll
  for (int rt = 0; rt < 2; ++rt)
#pragma unroll
    for (int j = 0; j < 4; ++j) {
      float p = 0.f;
#pragma unroll
      for (int ct = 0; ct < 8; ++ct)
        p = fmaf(fmaxf(acc[rt][ct][j] + a2bv[ct], 0.f), a3v[ct], p);
      p += __shfl_xor(p, 1);
      p += __shfl_xor(p, 2);
      p += __shfl_xor(p, 4);
      p += __shfl_xor(p, 8);
      if (lrow == 0)
        scores[row0 + wave * 32 + rt * 16 + kg * 4 + j] = p + a3b;
    }
}

// ---------------------------------------------------------------------------
// Fused softmax(T) + ctx reduction + concat -> comb = [y, ctx] ([64,1024]).
// Grid: 128 blocks = (b, half of D). Each block redundantly does softmax.
// ---------------------------------------------------------------------------
__global__ __launch_bounds__(256) void softmax_ctx(
    const float* __restrict__ scores, const float* __restrict__ enc_x,
    const float* __restrict__ y, float* __restrict__ comb) {
  const int b = blockIdx.x >> 1;
  const int half = blockIdx.x & 1;
  const int tid = threadIdx.x;
  __shared__ float att[512];
  __shared__ float red[256];
  const float v0 = scores[tid * 64 + b];
  const float v1 = scores[(tid + 256) * 64 + b];
  red[tid] = fmaxf(v0, v1);
  __syncthreads();
  for (int s = 128; s > 0; s >>= 1) {
    if (tid < s) red[tid] = fmaxf(red[tid], red[tid + s]);
    __syncthreads();
  }
  const float m = red[0];
  __syncthreads();
  const float e0 = __expf(v0 - m), e1 = __expf(v1 - m);
  red[tid] = e0 + e1;
  __syncthreads();
  for (int s = 128; s > 0; s >>= 1) {
    if (tid < s) red[tid] += red[tid + s];
    __syncthreads();
  }
  const float inv = 1.f / red[0];
  att[tid] = e0 * inv;
  att[tid + 256] = e1 * inv;
  __syncthreads();

  const int d = half * 256 + tid;
  float c0 = 0.f, c1 = 0.f;
  for (int t = 0; t < 512; t += 2) {
    c0 = fmaf(att[t], enc_x[(t * 64 + b) * 512 + d], c0);
    c1 = fmaf(att[t + 1], enc_x[((t + 1) * 64 + b) * 512 + d], c1);
  }
  comb[b * 1024 + 512 + d] = c0 + c1;
  comb[b * 1024 + d] = y[b * 512 + d];
}

// ---------------------------------------------------------------------------
// GRU gate fusion: h = (1-z)*n + z*h, optional output write.
// ---------------------------------------------------------------------------
__global__ __launch_bounds__(256) void gate_kernel(
    const float* __restrict__ gi, const float* __restrict__ gh,
    float* __restrict__ h, float* __restrict__ out) {
  const int idx = blockIdx.x * 256 + threadIdx.x;  // 0..32767
  const int b = idx >> 9, j = idx & 511;
  const int base = b * 1536;
  const float ir = gi[base + j], iz = gi[base + 512 + j],
              in_ = gi[base + 1024 + j];
  const float hr = gh[base + j], hz = gh[base + 512 + j],
              hn = gh[base + 1024 + j];
  const float r = 1.f / (1.f + expf(-(ir + hr)));
  const float z = 1.f / (1.f + expf(-(iz + hz)));
  const float n = tanhf(in_ + r * hn);
  const float hnew = (1.f - z) * n + z * h[idx];
  h[idx] = hnew;
  if (out) out[idx] = hnew;
}

__global__ __launch_bounds__(256) void init_kernel(
    const float* __restrict__ enc_x, float* __restrict__ y0,
    float* __restrict__ h0, float* __restrict__ h1) {
  const int idx = blockIdx.x * 256 + threadIdx.x;  // 0..32767
  y0[idx] = 0.f;
  const float v = enc_x[511 * 32768 + idx];
  h0[idx] = v;
  h1[idx] = v;
}

// ---------------------------------------------------------------------------
extern "C" void kernel_launch(void* const* d_in, const int* in_sizes, int n_in,
                              void* d_out, int out_size, void* d_ws,
                              size_t ws_size, hipStream_t stream) {
  const float* enc_x = (const float*)d_in[0];
  const float* a1_w = (const float*)d_in[2];
  const float* a1_b = (const float*)d_in[3];
  const float* a2_w = (const float*)d_in[4];
  const float* a2_b = (const float*)d_in[5];
  const float* a3_w = (const float*)d_in[6];
  const float* a3_b = (const float*)d_in[7];
  const float* t1_w = (const float*)d_in[8];
  const float* t1_b = (const float*)d_in[9];
  const float* t2_w = (const float*)d_in[10];
  const float* t2_b = (const float*)d_in[11];
  const float* w_ih = (const float*)d_in[12];
  const float* w_hh = (const float*)d_in[13];
  const float* b_ih = (const float*)d_in[14];
  const float* b_hh = (const float*)d_in[15];
  float* out = (float*)d_out;

  float* ws = (float*)d_ws;
  float* encproj = ws; ws += TB * 512;  // 16.7M floats
  float* yproj = ws;   ws += 64 * 512;
  float* scores = ws;  ws += TB;
  float* comb = ws;    ws += 64 * 1024;
  float* x1 = ws;      ws += 64 * 512;
  float* xv = ws;      ws += 64 * 512;
  float* gi = ws;      ws += 64 * 1536;
  float* gh = ws;      ws += 64 * 1536;
  float* h0 = ws;      ws += 64 * 512;
  float* h1 = ws;      ws += 64 * 512;
  float* y0 = ws;      ws += 64 * 512;
  short* bThi = (short*)ws; ws += 64 * 512;  // 128*512 shorts = 32K floats
  short* bTlo = (short*)ws; ws += 64 * 512;

  init_kernel<<<128, 256, 0, stream>>>(enc_x, y0, h0, h1);
  split_a2w<<<256, 256, 0, stream>>>(a2_w, bThi, bTlo);
  // encproj = enc_x @ a1_w[D:, :] + a1_b   (step-invariant, done once)
  gemm64<false, false><<<dim3(512, 8), 256, 0, stream>>>(
      enc_x, a1_w + 512 * 512, a1_b, encproj, TB, 512, 512);

  for (int t = 0; t < SEQ_LEN; ++t) {
    const float* y = (t == 0) ? y0 : h1;
    // yproj = y @ a1_w[:D, :]
    gemm64<false, false><<<dim3(1, 8), 256, 0, stream>>>(
        y, a1_w, nullptr, yproj, 64, 512, 512);
    scores_mfma<<<256, 256, 0, stream>>>(encproj, yproj, bThi, bTlo, a2_b,
                                         a3_w, a3_b, scores);
    softmax_ctx<<<128, 256, 0, stream>>>(scores, enc_x, y, comb);
    // transform MLP
    gemm64<false, true><<<dim3(1, 8), 256, 0, stream>>>(
        comb, t1_w, t1_b, x1, 64, 512, 1024);
    gemm64<false, true><<<dim3(1, 8), 256, 0, stream>>>(
        x1, t2_w, t2_b, xv, 64, 512, 512);
    // GRU layer 0
    gru_pair<<<dim3(1, 24, 2), 256, 0, stream>>>(
        xv, w_ih, b_ih, gi, h0, w_hh, b_hh, gh);
    gate_kernel<<<128, 256, 0, stream>>>(gi, gh, h0, nullptr);
    // GRU layer 1
    gru_pair<<<dim3(1, 24, 2), 256, 0, stream>>>(
        h0, w_ih + 1536 * 512, b_ih + 1536, gi,
        h1, w_hh + 1536 * 512, b_hh + 1536, gh);
    gate_kernel<<<128, 256, 0, stream>>>(gi, gh, h1, out + t * TB);
  }
}